// Round 2
// baseline (261.201 us; speedup 1.0000x reference)
//
#include <hip/hip_runtime.h>

// ---------------------------------------------------------------------------
// LSTM (Alex Graves) single step, batch 8192 — fused GEMM+epilogue, r7.
// r6 geometry (256x256 tile, 8 waves, verified epilogue) + counted-vmcnt
// pipeline (T4): raw s_barrier (NO vmcnt drain) + s_waitcnt vmcnt(8) so the
// next tile's 8 global_load_lds stay in flight across every barrier.
// r6's __syncthreads-per-step drained vmcnt(0) each K-step — the documented
// 2-phase trap (m228d/m230: 622-682 TF vs counted-schedule 1563+).
// + T1 XCD-bijective block swizzle (256 blocks, chunk 32: each XCD keeps
//   4 A-panels + all of B resident in its private L2).
// + T5 setprio around each 16-MFMA cluster (phase-split makes it pay).
//   A = [H | x[:,n,:]]  (8192 x 768)  fp16-packed
//   W rows permuted:  row c = gate g=(c>>4)&3, unit jj=((c>>6)<<4)|(c&15)
//   out[0:8192*512) = cm ; out[8192*512:) = h
// ---------------------------------------------------------------------------

typedef _Float16 half8 __attribute__((ext_vector_type(8)));
typedef _Float16 half4v __attribute__((ext_vector_type(4)));
typedef float floatx4 __attribute__((ext_vector_type(4)));

#define BATCH 8192
#define NSTEPS 16
#define IN_F 256
#define OUT_F 512
#define KDIM 768    // OUT_F + IN_F
#define NDIM 2048   // 4 * OUT_F
#define HSIZE ((size_t)BATCH * OUT_F)

#define BM 256
#define BN 256
#define BK 64
#define NKT (KDIM / BK)   // 12

__device__ __forceinline__ void async_copy16(const void* gptr, void* lptr) {
  __builtin_amdgcn_global_load_lds(
      (const __attribute__((address_space(1))) unsigned int*)gptr,
      (__attribute__((address_space(3))) unsigned int*)lptr,
      16, 0, 0);
}

__device__ __forceinline__ float sigmoidf_(float x) {
  return 1.0f / (1.0f + __expf(-x));
}

__device__ __forceinline__ float tanhf_(float x) {
  x = fminf(fmaxf(x, -20.0f), 20.0f);   // __expf(|2x|>~176) would inf->NaN
  float e = __expf(2.0f * x);
  return (e - 1.0f) / (e + 1.0f);
}

// ------------------- merged pack: A rows then W rows -----------------------
#define PACK_ROWS 8
__global__ void pack_AW(const float* __restrict__ H, const float* __restrict__ x,
                        const int* __restrict__ nptr,
                        const float* __restrict__ fg_w_h, const float* __restrict__ fg_w_x,
                        const float* __restrict__ ig_w_h, const float* __restrict__ ig_w_x,
                        const float* __restrict__ in_w_h, const float* __restrict__ in_w_x,
                        const float* __restrict__ og_w_h, const float* __restrict__ og_w_x,
                        _Float16* __restrict__ A, _Float16* __restrict__ W) {
  const int k = threadIdx.x * 4;
  const int n = *nptr;
  const int row0 = blockIdx.x * PACK_ROWS;
#pragma unroll
  for (int rr = 0; rr < PACK_ROWS; ++rr) {
    const int blk = row0 + rr;
    const float* src;
    _Float16* dst;
    if (blk < BATCH) {
      const int b = blk;
      if (k < OUT_F) {
        src = H + (size_t)b * OUT_F + k;
      } else {
        src = x + ((size_t)b * NSTEPS + n) * IN_F + (k - OUT_F);
      }
      dst = A + (size_t)b * KDIM + k;
    } else {
      const int row = blk - BATCH;
      const int g  = (row >> 4) & 3;
      const int jj = ((row >> 6) << 4) | (row & 15);
      if (k < OUT_F) {
        const float* wh = (g == 0) ? fg_w_h : (g == 1) ? ig_w_h : (g == 2) ? in_w_h : og_w_h;
        src = wh + (size_t)jj * OUT_F + k;
      } else {
        const float* wx = (g == 0) ? fg_w_x : (g == 1) ? ig_w_x : (g == 2) ? in_w_x : og_w_x;
        src = wx + (size_t)jj * IN_F + (k - OUT_F);
      }
      dst = W + (size_t)row * KDIM + k;
    }
    float4 v = *(const float4*)src;
    half4v h = {(_Float16)v.x, (_Float16)v.y, (_Float16)v.z, (_Float16)v.w};
    *(half4v*)dst = h;
  }
}

// ---------------------- fused GEMM + gate epilogue -------------------------
// 256x256 tile, BK=64, 512 thr / 8 waves (2M x 4N), each wave 128x64.
// LDS: 2 x (As 32KB + Bs 32KB) = 128 KB double-buffer.
// Pipeline ledger (race-checked):
//   iter t: issue stage(t+1)->buf[(t+1)&1]   [buffer's last reader was tile
//           t-1; all its reads completed before iter t-1's END barrier,
//           which every wave passed before reaching this point]
//           s_waitcnt vmcnt(8)               [per-wave: own 8 loads of tile t
//           arrived; tile t+1's 8 remain in flight — never drains mid-loop]
//           s_barrier                        [cross-wave: ALL shares of tile
//           t are in LDS]
//           4 x { ds_read frag; s_barrier; setprio(1); 16 MFMA; setprio(0) }
//           s_barrier                        [all reads of buf[t&1] complete:
//           gates the next iteration's stage-overwrite]
// ds_reads are plain loads -> compiler inserts exact lgkmcnt before MFMA use.
__global__ __launch_bounds__(512, 2) void gemm_lstm(
    const _Float16* __restrict__ A, const _Float16* __restrict__ W,
    const float* __restrict__ C,
    const float* __restrict__ fg_w_c, const float* __restrict__ fg_b,
    const float* __restrict__ ig_w_c, const float* __restrict__ ig_b,
    const float* __restrict__ in_b,
    const float* __restrict__ og_w_cn, const float* __restrict__ og_b,
    float* __restrict__ out) {
  __shared__ __align__(16) char smem[131072];

  const int tid = threadIdx.x;
  const int lane = tid & 63;
  const int wave = tid >> 6;       // 0..7
  const int quad = lane >> 4;
  const int l16 = lane & 15;
  const int wm = wave >> 2;        // 0..1  (M half: 128 rows)
  const int wn = wave & 3;         // 0..3  (N quarter: 64 cols)

  // T1: bijective XCD swizzle. 256 blocks, 8 XCDs, chunk=32: XCD x owns
  // swz in [x*32, x*32+32) = 4 consecutive M-panels x all 8 N-tiles.
  const int bid = blockIdx.x;
  const int swz = (bid & 7) * 32 + (bid >> 3);
  const int bx = swz & 7;          // N-tile 0..7
  const int by = swz >> 3;         // M-tile 0..31
  const int m0 = by * BM;
  const int n0 = bx * BN;

  // this lane's output unit (wave's 64 N-cols = 16 units x 4 gates)
  const int jj = (((n0 + wn * 64) >> 6) << 4) | l16;
  const float fwc = fg_w_c[jj], fb = fg_b[jj];
  const float iwc = ig_w_c[jj], ib = ig_b[jj];
  const float nb  = in_b[jj];
  const float owc = og_w_cn[jj], ob = og_b[jj];

  floatx4 acc[8][4] = {};

  auto stage = [&](int p, int t) {
    _Float16* As = (_Float16*)(smem + p * 65536);
    _Float16* Bs = (_Float16*)(smem + p * 65536 + 32768);
    const int kt = t * BK;
#pragma unroll
    for (int r = 0; r < 4; ++r) {
      const int g = r * 512 + tid;       // 16B granule index, lane-linear LDS
      const int row = g >> 3;            // 0..255
      const int cl = g & 7;
      const int cg = cl ^ (row & 7);     // swizzle on the GLOBAL side (m173)
      async_copy16(A + (size_t)(m0 + row) * KDIM + kt + cg * 8, As + g * 8);
      async_copy16(W + (size_t)(n0 + row) * KDIM + kt + cg * 8, Bs + g * 8);
    }
  };

  stage(0, 0);   // prologue: tile 0 in flight

  for (int t = 0; t < NKT; ++t) {
    if (t + 1 < NKT) {
      stage((t + 1) & 1, t + 1);                       // depth-1 prefetch
      asm volatile("s_waitcnt vmcnt(8)" ::: "memory"); // tile t arrived (own)
    } else {
      asm volatile("s_waitcnt vmcnt(0)" ::: "memory"); // final drain
    }
    asm volatile("s_barrier" ::: "memory");            // tile t visible to all

    const _Float16* As = (const _Float16*)(smem + (t & 1) * 65536);
    const _Float16* Bs = (const _Float16*)(smem + (t & 1) * 65536 + 32768);

    half8 bf[4];
#pragma unroll
    for (int ks = 0; ks < 2; ++ks) {
#pragma unroll
      for (int ih = 0; ih < 2; ++ih) {
        if (ih == 0) {   // bf reused across both i-halves of this ks
#pragma unroll
          for (int j = 0; j < 4; ++j) {
            const int row = wn * 64 + j * 16 + l16;
            const int chunk = ks * 4 + quad;
            const int gran = row * 8 + (chunk ^ (row & 7));
            bf[j] = *(const half8*)(Bs + gran * 8);
          }
        }
        half8 af[4];
#pragma unroll
        for (int i = 0; i < 4; ++i) {
          const int row = wm * 128 + (ih * 4 + i) * 16 + l16;
          const int chunk = ks * 4 + quad;
          const int gran = row * 8 + (chunk ^ (row & 7));
          af[i] = *(const half8*)(As + gran * 8);
        }
        asm volatile("s_barrier" ::: "memory");        // phase align (b1)
        __builtin_amdgcn_s_setprio(1);
#pragma unroll
        for (int i = 0; i < 4; ++i)
#pragma unroll
          for (int j = 0; j < 4; ++j)
            acc[ih * 4 + i][j] = __builtin_amdgcn_mfma_f32_16x16x32_f16(
                af[i], bf[j], acc[ih * 4 + i][j], 0, 0, 0);
        __builtin_amdgcn_s_setprio(0);
      }
    }
    asm volatile("s_barrier" ::: "memory");  // all buf[t&1] reads done: gates
                                             // next iter's stage-overwrite
  }

  // ---- epilogue. C/D: col=lane&15 (=jj lane), row=quad*4+r ----
  // Final tile-end barrier fenced all LDS reads; vmcnt queue is empty.
  float* cmS = (float*)smem;              // 256 x 64
  float* hS  = (float*)(smem + 65536);    // 256 x 64

  const int jjloc = wn * 16 + l16;        // 0..63 within block tile
#pragma unroll
  for (int i = 0; i < 8; ++i) {
    const int rbase = m0 + wm * 128 + i * 16 + quad * 4;
    float cv[4];
#pragma unroll
    for (int r = 0; r < 4; ++r)
      cv[r] = C[(size_t)(rbase + r) * OUT_F + jj];
#pragma unroll
    for (int r = 0; r < 4; ++r) {
      const float c = cv[r];
      const float inn = tanhf_(acc[i][2][r] + nb);
      const float fg  = sigmoidf_(fwc * c + acc[i][0][r] + fb);
      const float ig  = sigmoidf_(iwc * c + acc[i][1][r] + ib);
      const float cm  = fg * c + ig * inn;
      const float og  = sigmoidf_(owc * cm + acc[i][3][r] + ob);
      const int rloc = wm * 128 + i * 16 + quad * 4 + r;
      cmS[rloc * 64 + jjloc] = cm;
      hS [rloc * 64 + jjloc] = og * tanhf_(cm);
    }
  }
  __syncthreads();

  // cooperative coalesced store: 256 rows x 64 cols; 256B contiguous per row.
  const int ub = bx * 64;
#pragma unroll
  for (int q = 0; q < 8; ++q) {
    const int idx = q * 512 + tid;
    const int row = idx >> 4;            // 0..255
    const int c4 = idx & 15;             // float4 slot within row
    const size_t gbase = (size_t)(m0 + row) * OUT_F + ub + c4 * 4;
    *(float4*)(out + gbase) = *(const float4*)(cmS + row * 64 + c4 * 4);
    *(float4*)(out + HSIZE + gbase) = *(const float4*)(hS + row * 64 + c4 * 4);
  }
}

// ---------------------------------------------------------------------------
extern "C" void kernel_launch(void* const* d_in, const int* in_sizes, int n_in,
                              void* d_out, int out_size, void* d_ws, size_t ws_size,
                              hipStream_t stream) {
  const float* x       = (const float*)d_in[0];
  const float* C       = (const float*)d_in[1];
  const float* H       = (const float*)d_in[2];
  const float* fg_w_c  = (const float*)d_in[3];
  const float* fg_w_h  = (const float*)d_in[4];
  const float* fg_w_x  = (const float*)d_in[5];
  const float* fg_b    = (const float*)d_in[6];
  const float* ig_w_c  = (const float*)d_in[7];
  const float* ig_w_h  = (const float*)d_in[8];
  const float* ig_w_x  = (const float*)d_in[9];
  const float* ig_b    = (const float*)d_in[10];
  const float* in_w_h  = (const float*)d_in[11];
  const float* in_w_x  = (const float*)d_in[12];
  const float* in_b    = (const float*)d_in[13];
  const float* og_w_cn = (const float*)d_in[14];
  const float* og_w_h  = (const float*)d_in[15];
  const float* og_w_x  = (const float*)d_in[16];
  const float* og_b    = (const float*)d_in[17];
  const int*   nptr    = (const int*)d_in[18];

  char* ws = (char*)d_ws;
  _Float16* Apk = (_Float16*)ws;                // 8192*768*2 = 12,582,912 B
  _Float16* Wpk = (_Float16*)(ws + 12582912);   // 2048*768*2 =  3,145,728 B
  (void)ws_size; (void)in_sizes; (void)n_in; (void)out_size;

  pack_AW<<<(BATCH + NDIM) / PACK_ROWS, 192, 0, stream>>>(
      H, x, nptr,
      fg_w_h, fg_w_x, ig_w_h, ig_w_x,
      in_w_h, in_w_x, og_w_h, og_w_x,
      Apk, Wpk);
  gemm_lstm<<<dim3(256), 512, 0, stream>>>(Apk, Wpk, C,
                                           fg_w_c, fg_b, ig_w_c, ig_b, in_b,
                                           og_w_cn, og_b, (float*)d_out);
}